// Round 1
// baseline (451.786 us; speedup 1.0000x reference)
//
#include <hip/hip_runtime.h>
#include <hip/hip_bf16.h>

#define DI __device__ __forceinline__

typedef __attribute__((ext_vector_type(8))) short bf16x8;
typedef __attribute__((ext_vector_type(4))) float f32x4;
typedef __attribute__((ext_vector_type(4))) short s16x4;

constexpr int S  = 1024;
constexpr int NH = 71;
constexpr int HD = 64;
constexpr int H  = NH * HD;        // 4544
constexpr int F  = (NH + 2) * HD;  // 4672
constexpr float SCALE = 0.125f;    // 1/sqrt(64)

DI short f2bf(float f) {
  union { float f; unsigned u; } v; v.f = f;
  unsigned r = v.u + 0x7fffu + ((v.u >> 16) & 1u);
  return (short)(r >> 16);
}

DI void gload_lds16(const void* g, void* l) {
  __builtin_amdgcn_global_load_lds(
      (const __attribute__((address_space(1))) unsigned int*)g,
      (__attribute__((address_space(3))) unsigned int*)l, 16, 0, 0);
}

// ---------------- cast x fp32 -> bf16 ----------------
__global__ void cast_x_kernel(const float* __restrict__ x, short* __restrict__ xb, int n4) {
  int i = blockIdx.x * blockDim.x + threadIdx.x;
  if (i >= n4) return;
  f32x4 v = ((const f32x4*)x)[i];
  s16x4 o = { f2bf(v.x), f2bf(v.y), f2bf(v.z), f2bf(v.w) };
  ((s16x4*)xb)[i] = o;
}

// ---------------- transpose + cast: W[K][N] fp32 -> Wt[N][K] bf16 ----------------
// K, N both multiples of 64.
__global__ __launch_bounds__(256) void transpose_cast_kernel(
    const float* __restrict__ W, short* __restrict__ Wt, int K, int N) {
  __shared__ float tile[64][65];
  int n0 = blockIdx.x * 64, k0 = blockIdx.y * 64;
  int c = threadIdx.x & 63, rg = threadIdx.x >> 6;
#pragma unroll
  for (int i = 0; i < 16; ++i) {
    int r = rg * 16 + i;
    tile[r][c] = W[(size_t)(k0 + r) * N + n0 + c];
  }
  __syncthreads();
#pragma unroll
  for (int i = 0; i < 16; ++i) {
    int r = rg * 16 + i;
    Wt[(size_t)(n0 + r) * K + k0 + c] = f2bf(tile[c][r]);
  }
}

// ---------------- RoPE tables: cos/sin [S][32] fp32 ----------------
__global__ void rope_tables_kernel(float* __restrict__ ct, float* __restrict__ st) {
  int s = blockIdx.x, i = threadIdx.x;  // 32 threads
  float invf = powf(10000.0f, -(float)i / 32.0f);
  float a = (float)s * invf;
  ct[s * 32 + i] = cosf(a);
  st[s * 32 + i] = sinf(a);
}

// ---------------- RoPE + pack: qkv fp32 [S][F] -> Q[NH][S][64], K[S][64], Vt[64][S] bf16 ----------------
__global__ __launch_bounds__(64) void rope_pack_kernel(
    const float* __restrict__ qkv, const float* __restrict__ ct, const float* __restrict__ st,
    short* __restrict__ Qb, short* __restrict__ Kb, short* __restrict__ Vt) {
  int s = blockIdx.y, hh = blockIdx.x, d = threadIdx.x;
  if (hh < NH + 1) {  // 0..70 = q heads; 71 = k (cols 4544..4607 = 71*64..)
    int col = hh * 64 + d;
    float v = qkv[(size_t)s * F + col];
    int i = d & 31;
    float c = ct[s * 32 + i], sn = st[s * 32 + i];
    float rot = (d < 32) ? -qkv[(size_t)s * F + col + 32] : qkv[(size_t)s * F + col - 32];
    short ob = f2bf(v * c + rot * sn);
    if (hh < NH) Qb[((size_t)hh * S + s) * 64 + d] = ob;
    else         Kb[(size_t)s * 64 + d] = ob;
  } else {  // v: cols 4608..4671, store transposed
    float v = qkv[(size_t)s * F + (NH + 1) * 64 + d];
    Vt[(size_t)d * S + s] = f2bf(v);
  }
}

// ---------------- GEMM: C[M][N] fp32 = A[M][K] bf16 * Bt[N][K]^T bf16 ----------------
// 128x128 tile, BK=32, 4 waves (2x2), 16x16x32 MFMA, global_load_lds staging.
// M % 128 == 0, K % 32 == 0; N tail handled (clamped staging + masked store).
__global__ __launch_bounds__(256) void gemm_bt_kernel(
    const short* __restrict__ A, const short* __restrict__ Bt, float* __restrict__ C,
    int M, int N, int K) {
  __shared__ short As[128 * 32];
  __shared__ short Bs[128 * 32];
  const int tid = threadIdx.x;
  const int lane = tid & 63;
  const int wave = tid >> 6;
  const int wr = wave >> 1, wc = wave & 1;
  const int tm = blockIdx.y, tn = blockIdx.x;
  const int lr = lane & 15, g = lane >> 4;

  f32x4 acc[4][4] = {};

  // staging: 512 16B-chunks, 2 per thread; chunk c -> LDS byte c*16, row c>>2, k-off (c&3)*8
  const int c0 = wave * 64 + lane;
  const int c1 = (wave + 4) * 64 + lane;
  const int ra0 = c0 >> 2, ka0 = (c0 & 3) * 8;
  const int ra1 = c1 >> 2, ka1 = (c1 & 3) * 8;

  const size_t Arow0 = (size_t)(tm * 128 + ra0) * K;
  const size_t Arow1 = (size_t)(tm * 128 + ra1) * K;
  int bn0 = tn * 128 + ra0; if (bn0 >= N) bn0 = N - 1;  // clamp: dup data, masked on store
  int bn1 = tn * 128 + ra1; if (bn1 >= N) bn1 = N - 1;
  const size_t Brow0 = (size_t)bn0 * K;
  const size_t Brow1 = (size_t)bn1 * K;

  char* AsB = (char*)As;
  char* BsB = (char*)Bs;

  for (int k0 = 0; k0 < K; k0 += 32) {
    gload_lds16(A + Arow0 + k0 + ka0, AsB + wave * 1024);
    gload_lds16(A + Arow1 + k0 + ka1, AsB + (wave + 4) * 1024);
    gload_lds16(Bt + Brow0 + k0 + ka0, BsB + wave * 1024);
    gload_lds16(Bt + Brow1 + k0 + ka1, BsB + (wave + 4) * 1024);
    __syncthreads();
    bf16x8 af[4], bfr[4];
#pragma unroll
    for (int im = 0; im < 4; ++im)
      af[im] = *(const bf16x8*)(As + (wr * 64 + im * 16 + lr) * 32 + g * 8);
#pragma unroll
    for (int in = 0; in < 4; ++in)
      bfr[in] = *(const bf16x8*)(Bs + (wc * 64 + in * 16 + lr) * 32 + g * 8);
#pragma unroll
    for (int im = 0; im < 4; ++im)
#pragma unroll
      for (int in = 0; in < 4; ++in)
        acc[im][in] = __builtin_amdgcn_mfma_f32_16x16x32_bf16(af[im], bfr[in], acc[im][in], 0, 0, 0);
    __syncthreads();
  }

#pragma unroll
  for (int im = 0; im < 4; ++im) {
#pragma unroll
    for (int in = 0; in < 4; ++in) {
      int row = tm * 128 + wr * 64 + im * 16 + g * 4;
      int col = tn * 128 + wc * 64 + in * 16 + lr;
      if (col < N) {
#pragma unroll
        for (int i = 0; i < 4; ++i)
          C[(size_t)(row + i) * N + col] = acc[im][in][i];
      }
    }
  }
}

// ---------------- fused causal MQA attention ----------------
// block = (q-tile of 64 rows, head); 4 waves x 16 q-rows; KV blocks of 128 keys.
__global__ __launch_bounds__(256) void attn_kernel(
    const short* __restrict__ Qb,  // [NH][S][64]
    const short* __restrict__ Kb,  // [S][64]
    const short* __restrict__ Vt,  // [64][S]
    short* __restrict__ merged) {  // [S][H] bf16
  __shared__ short Pl[4][16 * 128];
  const int h = blockIdx.y, qt = blockIdx.x;
  const int lane = threadIdx.x & 63, w = threadIdx.x >> 6;
  const int lr = lane & 15, g = lane >> 4;
  const int q0 = qt * 64 + w * 16;

  const short* qrow = Qb + ((size_t)h * S + q0 + lr) * 64 + g * 8;
  bf16x8 aQ0 = *(const bf16x8*)(qrow);
  bf16x8 aQ1 = *(const bf16x8*)(qrow + 32);

  f32x4 accO[4] = {};
  float m4[4] = {-3e30f, -3e30f, -3e30f, -3e30f};
  float l4[4] = {0.f, 0.f, 0.f, 0.f};

  const int kbmax = (qt * 64 + 63) >> 7;
  for (int kb = 0; kb <= kbmax; ++kb) {
    const int key0 = kb * 128;
    f32x4 sc[8];
#pragma unroll
    for (int nf = 0; nf < 8; ++nf) {
      const short* krow = Kb + (size_t)(key0 + nf * 16 + lr) * 64 + g * 8;
      bf16x8 b0 = *(const bf16x8*)(krow);
      bf16x8 b1 = *(const bf16x8*)(krow + 32);
      f32x4 z = {};
      z = __builtin_amdgcn_mfma_f32_16x16x32_bf16(aQ0, b0, z, 0, 0, 0);
      sc[nf] = __builtin_amdgcn_mfma_f32_16x16x32_bf16(aQ1, b1, z, 0, 0, 0);
    }
    // scale + causal mask + row max (rows live at (g*4+i), cols at (nf*16+lr))
    float pm[4] = {-3e30f, -3e30f, -3e30f, -3e30f};
#pragma unroll
    for (int nf = 0; nf < 8; ++nf)
#pragma unroll
      for (int i = 0; i < 4; ++i) {
        int qg = q0 + g * 4 + i;
        int key = key0 + nf * 16 + lr;
        float sv = sc[nf][i] * SCALE + (key <= qg ? 0.0f : -1e9f);
        sc[nf][i] = sv;
        pm[i] = fmaxf(pm[i], sv);
      }
#pragma unroll
    for (int i = 0; i < 4; ++i) {
      pm[i] = fmaxf(pm[i], __shfl_xor(pm[i], 1));
      pm[i] = fmaxf(pm[i], __shfl_xor(pm[i], 2));
      pm[i] = fmaxf(pm[i], __shfl_xor(pm[i], 4));
      pm[i] = fmaxf(pm[i], __shfl_xor(pm[i], 8));
    }
    float scl[4], rs[4] = {0.f, 0.f, 0.f, 0.f};
#pragma unroll
    for (int i = 0; i < 4; ++i) {
      float mn = fmaxf(m4[i], pm[i]);
      scl[i] = __expf(m4[i] - mn);
      m4[i] = mn;
    }
#pragma unroll
    for (int nf = 0; nf < 8; ++nf)
#pragma unroll
      for (int i = 0; i < 4; ++i) {
        float p = __expf(sc[nf][i] - m4[i]);
        rs[i] += p;
        Pl[w][(g * 4 + i) * 128 + nf * 16 + lr] = f2bf(p);
      }
#pragma unroll
    for (int i = 0; i < 4; ++i) {
      rs[i] += __shfl_xor(rs[i], 1);
      rs[i] += __shfl_xor(rs[i], 2);
      rs[i] += __shfl_xor(rs[i], 4);
      rs[i] += __shfl_xor(rs[i], 8);
      l4[i] = l4[i] * scl[i] + rs[i];
    }
#pragma unroll
    for (int df = 0; df < 4; ++df)
#pragma unroll
      for (int i = 0; i < 4; ++i)
        accO[df][i] *= scl[i];
    __syncthreads();  // P writes visible (per-wave buffer; uniform trip count per block)
#pragma unroll
    for (int kk = 0; kk < 4; ++kk) {
      bf16x8 aP = *(const bf16x8*)(&Pl[w][lr * 128 + kk * 32 + g * 8]);
#pragma unroll
      for (int df = 0; df < 4; ++df) {
        bf16x8 bV = *(const bf16x8*)(Vt + (size_t)(df * 16 + lr) * S + key0 + kk * 32 + g * 8);
        accO[df] = __builtin_amdgcn_mfma_f32_16x16x32_bf16(aP, bV, accO[df], 0, 0, 0);
      }
    }
    __syncthreads();
  }
#pragma unroll
  for (int df = 0; df < 4; ++df)
#pragma unroll
    for (int i = 0; i < 4; ++i) {
      int qg = q0 + g * 4 + i;
      int d = df * 16 + lr;
      merged[(size_t)qg * H + h * 64 + d] = f2bf(accO[df][i] / l4[i]);
    }
}

extern "C" void kernel_launch(void* const* d_in, const int* in_sizes, int n_in,
                              void* d_out, int out_size, void* d_ws, size_t ws_size,
                              hipStream_t stream) {
  const float* x    = (const float*)d_in[0];
  const float* wqkv = (const float*)d_in[1];
  const float* wd   = (const float*)d_in[2];
  // d_in[3] attention_mask: pure causal, applied analytically in attn_kernel
  float* out = (float*)d_out;

  char* ws = (char*)d_ws;
  size_t off = 0;
  short* Wqkvt  = (short*)(ws + off); off += (size_t)F * H * 2;       // [F][H]
  short* Wdt    = (short*)(ws + off); off += (size_t)H * H * 2;       // [H][H]
  short* xb     = (short*)(ws + off); off += (size_t)S * H * 2;       // [S][H]
  float* qkv    = (float*)(ws + off); off += (size_t)S * F * 4;       // [S][F]
  short* Qb     = (short*)(ws + off); off += (size_t)NH * S * HD * 2; // [NH][S][64]
  short* Kb     = (short*)(ws + off); off += (size_t)S * HD * 2;      // [S][64]
  short* Vtb    = (short*)(ws + off); off += (size_t)HD * S * 2;      // [64][S]
  short* merged = (short*)(ws + off); off += (size_t)S * H * 2;       // [S][H]
  float* ct     = (float*)(ws + off); off += (size_t)S * 32 * 4;
  float* st     = (float*)(ws + off); off += (size_t)S * 32 * 4;
  (void)ws_size; (void)in_sizes; (void)n_in; (void)out_size;

  hipLaunchKernelGGL(cast_x_kernel, dim3((S * H / 4 + 255) / 256), dim3(256), 0, stream,
                     x, xb, S * H / 4);
  hipLaunchKernelGGL(transpose_cast_kernel, dim3(F / 64, H / 64), dim3(256), 0, stream,
                     wqkv, Wqkvt, H, F);
  hipLaunchKernelGGL(transpose_cast_kernel, dim3(H / 64, H / 64), dim3(256), 0, stream,
                     wd, Wdt, H, H);
  hipLaunchKernelGGL(rope_tables_kernel, dim3(S), dim3(32), 0, stream, ct, st);
  hipLaunchKernelGGL(gemm_bt_kernel, dim3((F + 127) / 128, S / 128), dim3(256), 0, stream,
                     xb, Wqkvt, qkv, S, F, H);
  hipLaunchKernelGGL(rope_pack_kernel, dim3(NH + 2, S), dim3(64), 0, stream,
                     qkv, ct, st, Qb, Kb, Vtb);
  hipLaunchKernelGGL(attn_kernel, dim3(S / 64, NH), dim3(256), 0, stream,
                     Qb, Kb, Vtb, merged);
  hipLaunchKernelGGL(gemm_bt_kernel, dim3((H + 127) / 128, S / 128), dim3(256), 0, stream,
                     merged, Wdt, out, S, H, H);
}

// Round 2
// 399.451 us; speedup vs baseline: 1.1310x; 1.1310x over previous
//
#include <hip/hip_runtime.h>
#include <hip/hip_bf16.h>

#define DI __device__ __forceinline__

typedef __attribute__((ext_vector_type(8))) short bf16x8;
typedef __attribute__((ext_vector_type(4))) float f32x4;
typedef __attribute__((ext_vector_type(4))) short s16x4;

constexpr int S  = 1024;
constexpr int NH = 71;
constexpr int HD = 64;
constexpr int H  = NH * HD;        // 4544
constexpr int F  = (NH + 2) * HD;  // 4672
constexpr float SCALE = 0.125f;    // 1/sqrt(64)

DI short f2bf(float f) {
  union { float f; unsigned u; } v; v.f = f;
  unsigned r = v.u + 0x7fffu + ((v.u >> 16) & 1u);
  return (short)(r >> 16);
}

DI void gload_lds16(const void* g, void* l) {
  __builtin_amdgcn_global_load_lds(
      (const __attribute__((address_space(1))) unsigned int*)g,
      (__attribute__((address_space(3))) unsigned int*)l, 16, 0, 0);
}

// ---------------- cast x fp32 -> bf16 ----------------
__global__ void cast_x_kernel(const float* __restrict__ x, short* __restrict__ xb, int n4) {
  int i = blockIdx.x * blockDim.x + threadIdx.x;
  if (i >= n4) return;
  f32x4 v = ((const f32x4*)x)[i];
  s16x4 o = { f2bf(v.x), f2bf(v.y), f2bf(v.z), f2bf(v.w) };
  ((s16x4*)xb)[i] = o;
}

// ---------------- transpose + cast: W[K][N] fp32 -> Wt[N][K] bf16 ----------------
__global__ __launch_bounds__(256) void transpose_cast_kernel(
    const float* __restrict__ W, short* __restrict__ Wt, int K, int N) {
  __shared__ float tile[64][65];
  int n0 = blockIdx.x * 64, k0 = blockIdx.y * 64;
  int c = threadIdx.x & 63, rg = threadIdx.x >> 6;
#pragma unroll
  for (int i = 0; i < 16; ++i) {
    int r = rg * 16 + i;
    tile[r][c] = W[(size_t)(k0 + r) * N + n0 + c];
  }
  __syncthreads();
#pragma unroll
  for (int i = 0; i < 16; ++i) {
    int r = rg * 16 + i;
    Wt[(size_t)(n0 + r) * K + k0 + c] = f2bf(tile[c][r]);
  }
}

// ---------------- RoPE tables: cos/sin [S][32] fp32 ----------------
__global__ void rope_tables_kernel(float* __restrict__ ct, float* __restrict__ st) {
  int s = blockIdx.x, i = threadIdx.x;  // 32 threads
  float invf = powf(10000.0f, -(float)i / 32.0f);
  float a = (float)s * invf;
  ct[s * 32 + i] = cosf(a);
  st[s * 32 + i] = sinf(a);
}

// ---------------- RoPE + pack: qkv fp32 [S][F] -> Q[NH][S][64], K[S][64], Vt[64][S] bf16 ----
__global__ __launch_bounds__(256) void rope_pack_kernel(
    const float* __restrict__ qkv, const float* __restrict__ ct, const float* __restrict__ st,
    short* __restrict__ Qb, short* __restrict__ Kb, short* __restrict__ Vt) {
  int s = blockIdx.x;
  const float* row = qkv + (size_t)s * F;
  for (int c = threadIdx.x; c < F; c += 256) {
    int hh = c >> 6, d = c & 63;
    float v = row[c];
    if (hh <= NH) {  // q heads 0..70, k at 71
      int i = d & 31;
      float cs = ct[s * 32 + i], sn = st[s * 32 + i];
      float rot = (d < 32) ? -row[c + 32] : row[c - 32];
      short ob = f2bf(v * cs + rot * sn);
      if (hh < NH) Qb[((size_t)hh * S + s) * 64 + d] = ob;
      else         Kb[(size_t)s * 64 + d] = ob;
    } else {  // v: store transposed
      Vt[(size_t)d * S + s] = f2bf(v);
    }
  }
}

// ---------------- GEMM: C[M][N] fp32 = A[M][K] bf16 * Bt[N][K]^T bf16 ----------------
// BM=128, BN=64, BK=32; 4 waves (2x2), 16x16x32 MFMA, global_load_lds staging.
// Requires M%128==0, N%64==0, K%32==0 (all hold: M=1024, N in {4672,4544}, K in {4544}).
__global__ __launch_bounds__(256) void gemm_bt_kernel(
    const short* __restrict__ A, const short* __restrict__ Bt, float* __restrict__ C,
    int M, int N, int K) {
  __shared__ short As[128 * 32];
  __shared__ short Bs[64 * 32];
  const int tid = threadIdx.x;
  const int lane = tid & 63;
  const int wave = tid >> 6;
  const int wr = wave >> 1, wc = wave & 1;
  const int lr = lane & 15, g = lane >> 4;

  // XCD-aware swizzle (bijective, nwg % 8 == 0): group blocks sharing B-panels per XCD.
  const int nwg = gridDim.x;
  int bid = blockIdx.x;
  int wgid = ((nwg & 7) == 0) ? ((bid & 7) * (nwg >> 3) + (bid >> 3)) : bid;
  const int ntm = M >> 7;
  const int tn = wgid / ntm;
  const int tm = wgid % ntm;

  f32x4 acc[4][2] = {};

  // staging chunk for this thread: c = wave*64+lane
  const int c0 = wave * 64 + lane;
  const int raA0 = c0 >> 2, kaA0 = (c0 & 3) * 8;          // A chunk 0 (rows 0..63)
  const int raA1 = (c0 + 256) >> 2, kaA1 = (c0 & 3) * 8;  // A chunk 1 (rows 64..127)
  const int rb = c0 >> 2, kb = (c0 & 3) * 8;              // B chunk (rows 0..63)

  const size_t Arow0 = (size_t)(tm * 128 + raA0) * K;
  const size_t Arow1 = (size_t)(tm * 128 + raA1) * K;
  const size_t Brow  = (size_t)(tn * 64 + rb) * K;

  char* AsB = (char*)As;
  char* BsB = (char*)Bs;

  for (int k0 = 0; k0 < K; k0 += 32) {
    gload_lds16(A + Arow0 + k0 + kaA0, AsB + wave * 1024);
    gload_lds16(A + Arow1 + k0 + kaA1, AsB + 4096 + wave * 1024);
    gload_lds16(Bt + Brow + k0 + kb, BsB + wave * 1024);
    __syncthreads();
    bf16x8 af[4], bfr[2];
#pragma unroll
    for (int im = 0; im < 4; ++im)
      af[im] = *(const bf16x8*)(As + (wr * 64 + im * 16 + lr) * 32 + g * 8);
#pragma unroll
    for (int in = 0; in < 2; ++in)
      bfr[in] = *(const bf16x8*)(Bs + (wc * 32 + in * 16 + lr) * 32 + g * 8);
#pragma unroll
    for (int im = 0; im < 4; ++im)
#pragma unroll
      for (int in = 0; in < 2; ++in)
        acc[im][in] = __builtin_amdgcn_mfma_f32_16x16x32_bf16(af[im], bfr[in], acc[im][in], 0, 0, 0);
    __syncthreads();
  }

#pragma unroll
  for (int im = 0; im < 4; ++im) {
#pragma unroll
    for (int in = 0; in < 2; ++in) {
      int row = tm * 128 + wr * 64 + im * 16 + g * 4;
      int col = tn * 64 + wc * 32 + in * 16 + lr;
#pragma unroll
      for (int i = 0; i < 4; ++i)
        C[(size_t)(row + i) * N + col] = acc[im][in][i];
    }
  }
}

// ---------------- fused causal MQA attention ----------------
// block = (q-tile of 64 rows, head); 4 INDEPENDENT waves x 16 q-rows; KV blocks of 128 keys.
// No barriers: each wave owns its own swizzled P slice in LDS.
DI int pswz(int row, int colshort) {
  // XOR swizzle within 256B row: write conflict-free, read at b128 floor.
  int byte = (colshort * 2) ^ (((row >> 2) & 3) << 5) ^ ((row & 3) << 4);
  return row * 128 + (byte >> 1);
}

__global__ __launch_bounds__(256) void attn_kernel(
    const short* __restrict__ Qb,  // [NH][S][64]
    const short* __restrict__ Kb,  // [S][64]
    const short* __restrict__ Vt,  // [64][S]
    short* __restrict__ merged) {  // [S][H] bf16
  __shared__ short Pl[4][16 * 128];
  const int h = blockIdx.y;
  const int qt = (int)(gridDim.x - 1 - blockIdx.x);  // heavy tiles launch first
  const int lane = threadIdx.x & 63, w = threadIdx.x >> 6;
  const int lr = lane & 15, g = lane >> 4;
  const int q0 = qt * 64 + w * 16;
  short* P = Pl[w];

  const short* qrow = Qb + ((size_t)h * S + q0 + lr) * 64 + g * 8;
  bf16x8 aQ0 = *(const bf16x8*)(qrow);
  bf16x8 aQ1 = *(const bf16x8*)(qrow + 32);

  f32x4 accO[4] = {};
  float m4[4] = {-3e30f, -3e30f, -3e30f, -3e30f};
  float l4[4] = {0.f, 0.f, 0.f, 0.f};

  const int kbmax = (qt * 64 + 63) >> 7;
  for (int kb = 0; kb <= kbmax; ++kb) {
    const int key0 = kb * 128;
    f32x4 sc[8];
#pragma unroll
    for (int nf = 0; nf < 8; ++nf) {
      const short* krow = Kb + (size_t)(key0 + nf * 16 + lr) * 64 + g * 8;
      bf16x8 b0 = *(const bf16x8*)(krow);
      bf16x8 b1 = *(const bf16x8*)(krow + 32);
      f32x4 z = {};
      z = __builtin_amdgcn_mfma_f32_16x16x32_bf16(aQ0, b0, z, 0, 0, 0);
      sc[nf] = __builtin_amdgcn_mfma_f32_16x16x32_bf16(aQ1, b1, z, 0, 0, 0);
    }
    // scale + causal mask + row max (row q = q0+g*4+i, col key = key0+nf*16+lr)
    float pm[4] = {-3e30f, -3e30f, -3e30f, -3e30f};
#pragma unroll
    for (int nf = 0; nf < 8; ++nf)
#pragma unroll
      for (int i = 0; i < 4; ++i) {
        int qg = q0 + g * 4 + i;
        int key = key0 + nf * 16 + lr;
        float sv = sc[nf][i] * SCALE + (key <= qg ? 0.0f : -1e9f);
        sc[nf][i] = sv;
        pm[i] = fmaxf(pm[i], sv);
      }
#pragma unroll
    for (int i = 0; i < 4; ++i) {
      pm[i] = fmaxf(pm[i], __shfl_xor(pm[i], 1));
      pm[i] = fmaxf(pm[i], __shfl_xor(pm[i], 2));
      pm[i] = fmaxf(pm[i], __shfl_xor(pm[i], 4));
      pm[i] = fmaxf(pm[i], __shfl_xor(pm[i], 8));
    }
    float scl[4], rs[4] = {0.f, 0.f, 0.f, 0.f};
#pragma unroll
    for (int i = 0; i < 4; ++i) {
      float mn = fmaxf(m4[i], pm[i]);
      scl[i] = __expf(m4[i] - mn);
      m4[i] = mn;
    }
#pragma unroll
    for (int nf = 0; nf < 8; ++nf)
#pragma unroll
      for (int i = 0; i < 4; ++i) {
        float p = __expf(sc[nf][i] - m4[i]);
        rs[i] += p;
        P[pswz(g * 4 + i, nf * 16 + lr)] = f2bf(p);
      }
#pragma unroll
    for (int i = 0; i < 4; ++i) {
      rs[i] += __shfl_xor(rs[i], 1);
      rs[i] += __shfl_xor(rs[i], 2);
      rs[i] += __shfl_xor(rs[i], 4);
      rs[i] += __shfl_xor(rs[i], 8);
      l4[i] = l4[i] * scl[i] + rs[i];
    }
#pragma unroll
    for (int df = 0; df < 4; ++df)
#pragma unroll
      for (int i = 0; i < 4; ++i)
        accO[df][i] *= scl[i];
    // intra-wave LDS write->read dependency; compiler inserts lgkmcnt waits (no barrier needed)
#pragma unroll
    for (int kk = 0; kk < 4; ++kk) {
      bf16x8 aP = *(const bf16x8*)(&P[pswz(lr, kk * 32 + g * 8)]);
#pragma unroll
      for (int df = 0; df < 4; ++df) {
        bf16x8 bV = *(const bf16x8*)(Vt + (size_t)(df * 16 + lr) * S + key0 + kk * 32 + g * 8);
        accO[df] = __builtin_amdgcn_mfma_f32_16x16x32_bf16(aP, bV, accO[df], 0, 0, 0);
      }
    }
  }
#pragma unroll
  for (int i = 0; i < 4; ++i) {
    float rl = 1.0f / l4[i];
#pragma unroll
    for (int df = 0; df < 4; ++df) {
      int qg = q0 + g * 4 + i;
      int d = df * 16 + lr;
      merged[(size_t)qg * H + h * 64 + d] = f2bf(accO[df][i] * rl);
    }
  }
}

extern "C" void kernel_launch(void* const* d_in, const int* in_sizes, int n_in,
                              void* d_out, int out_size, void* d_ws, size_t ws_size,
                              hipStream_t stream) {
  const float* x    = (const float*)d_in[0];
  const float* wqkv = (const float*)d_in[1];
  const float* wd   = (const float*)d_in[2];
  // d_in[3] attention_mask: pure causal, applied analytically in attn_kernel
  float* out = (float*)d_out;

  char* ws = (char*)d_ws;
  size_t off = 0;
  short* Wqkvt  = (short*)(ws + off); off += (size_t)F * H * 2;       // [F][H]
  short* Wdt    = (short*)(ws + off); off += (size_t)H * H * 2;       // [H][H]
  short* xb     = (short*)(ws + off); off += (size_t)S * H * 2;       // [S][H]
  float* qkv    = (float*)(ws + off); off += (size_t)S * F * 4;       // [S][F]
  short* Qb     = (short*)(ws + off); off += (size_t)NH * S * HD * 2; // [NH][S][64]
  short* Kb     = (short*)(ws + off); off += (size_t)S * HD * 2;      // [S][64]
  short* Vtb    = (short*)(ws + off); off += (size_t)HD * S * 2;      // [64][S]
  short* merged = (short*)(ws + off); off += (size_t)S * H * 2;       // [S][H]
  float* ct     = (float*)(ws + off); off += (size_t)S * 32 * 4;
  float* st     = (float*)(ws + off); off += (size_t)S * 32 * 4;
  (void)ws_size; (void)in_sizes; (void)n_in; (void)out_size;

  hipLaunchKernelGGL(cast_x_kernel, dim3((S * H / 4 + 255) / 256), dim3(256), 0, stream,
                     x, xb, S * H / 4);
  hipLaunchKernelGGL(transpose_cast_kernel, dim3(F / 64, H / 64), dim3(256), 0, stream,
                     wqkv, Wqkvt, H, F);
  hipLaunchKernelGGL(transpose_cast_kernel, dim3(H / 64, H / 64), dim3(256), 0, stream,
                     wd, Wdt, H, H);
  hipLaunchKernelGGL(rope_tables_kernel, dim3(S), dim3(32), 0, stream, ct, st);
  hipLaunchKernelGGL(gemm_bt_kernel, dim3((F / 64) * (S / 128)), dim3(256), 0, stream,
                     xb, Wqkvt, qkv, S, F, H);
  hipLaunchKernelGGL(rope_pack_kernel, dim3(S), dim3(256), 0, stream,
                     qkv, ct, st, Qb, Kb, Vtb);
  hipLaunchKernelGGL(attn_kernel, dim3(S / 64, NH), dim3(256), 0, stream,
                     Qb, Kb, Vtb, merged);
  hipLaunchKernelGGL(gemm_bt_kernel, dim3((H / 64) * (S / 128)), dim3(256), 0, stream,
                     merged, Wdt, out, S, H, H);
}

// Round 3
// 341.711 us; speedup vs baseline: 1.3221x; 1.1690x over previous
//
#include <hip/hip_runtime.h>
#include <hip/hip_bf16.h>

#define DI __device__ __forceinline__

typedef __attribute__((ext_vector_type(8))) short bf16x8;
typedef __attribute__((ext_vector_type(4))) float f32x4;
typedef __attribute__((ext_vector_type(4))) short s16x4;

constexpr int S  = 1024;
constexpr int NH = 71;
constexpr int HD = 64;
constexpr int H  = NH * HD;        // 4544
constexpr int F  = (NH + 2) * HD;  // 4672
constexpr float SCALE = 0.125f;    // 1/sqrt(64)
constexpr float K2 = 0.125f * 1.44269504f;  // SCALE * log2(e)

// split-K attention: unit = (head, 16 q-rows, 256 keys). per head: 160 units.
constexpr int UPH = 160;                 // units per head
constexpr int NU  = NH * UPH;            // 11360
__device__ __constant__ int d_off4[4] = {0, 64, 112, 144};

DI short f2bf(float f) {
  union { float f; unsigned u; } v; v.f = f;
  unsigned r = v.u + 0x7fffu + ((v.u >> 16) & 1u);
  return (short)(r >> 16);
}
DI float bf2f(short b) {
  union { unsigned u; float f; } v; v.u = ((unsigned)(unsigned short)b) << 16;
  return v.f;
}
DI unsigned cvt_pk_bf16(float lo, float hi) {
  unsigned r;
  asm("v_cvt_pk_bf16_f32 %0, %1, %2" : "=v"(r) : "v"(lo), "v"(hi));
  return r;
}

DI void gload_lds16(const void* g, void* l) {
  __builtin_amdgcn_global_load_lds(
      (const __attribute__((address_space(1))) unsigned int*)g,
      (__attribute__((address_space(3))) unsigned int*)l, 16, 0, 0);
}

// ---------------- cast x fp32 -> bf16 ----------------
__global__ void cast_x_kernel(const float* __restrict__ x, short* __restrict__ xb, int n4) {
  int i = blockIdx.x * blockDim.x + threadIdx.x;
  if (i >= n4) return;
  f32x4 v = ((const f32x4*)x)[i];
  s16x4 o = { f2bf(v.x), f2bf(v.y), f2bf(v.z), f2bf(v.w) };
  ((s16x4*)xb)[i] = o;
}

// ---------------- transpose + cast: W[K][N] fp32 -> Wt[N][K] bf16 ----------------
__global__ __launch_bounds__(256) void transpose_cast_kernel(
    const float* __restrict__ W, short* __restrict__ Wt, int K, int N) {
  __shared__ float tile[64][65];
  int n0 = blockIdx.x * 64, k0 = blockIdx.y * 64;
  int c = threadIdx.x & 63, rg = threadIdx.x >> 6;
#pragma unroll
  for (int i = 0; i < 16; ++i) {
    int r = rg * 16 + i;
    tile[r][c] = W[(size_t)(k0 + r) * N + n0 + c];
  }
  __syncthreads();
#pragma unroll
  for (int i = 0; i < 16; ++i) {
    int r = rg * 16 + i;
    Wt[(size_t)(n0 + r) * K + k0 + c] = f2bf(tile[c][r]);
  }
}

// ---------------- RoPE tables: cos/sin [S][32] fp32 ----------------
__global__ void rope_tables_kernel(float* __restrict__ ct, float* __restrict__ st) {
  int s = blockIdx.x, i = threadIdx.x;  // 32 threads
  float invf = powf(10000.0f, -(float)i / 32.0f);
  float a = (float)s * invf;
  ct[s * 32 + i] = cosf(a);
  st[s * 32 + i] = sinf(a);
}

// ---------------- RoPE + pack: qkv fp32 [S][F] -> Q[NH][S][64], K[S][64], Vt[64][S] bf16 ----
__global__ __launch_bounds__(256) void rope_pack_kernel(
    const float* __restrict__ qkv, const float* __restrict__ ct, const float* __restrict__ st,
    short* __restrict__ Qb, short* __restrict__ Kb, short* __restrict__ Vt) {
  int s = blockIdx.x;
  const float* row = qkv + (size_t)s * F;
  for (int c = threadIdx.x; c < F; c += 256) {
    int hh = c >> 6, d = c & 63;
    float v = row[c];
    if (hh <= NH) {  // q heads 0..70, k at 71
      int i = d & 31;
      float cs = ct[s * 32 + i], sn = st[s * 32 + i];
      float rot = (d < 32) ? -row[c + 32] : row[c - 32];
      short ob = f2bf(v * cs + rot * sn);
      if (hh < NH) Qb[((size_t)hh * S + s) * 64 + d] = ob;
      else         Kb[(size_t)s * 64 + d] = ob;
    } else {  // v: store transposed
      Vt[(size_t)d * S + s] = f2bf(v);
    }
  }
}

// ---------------- GEMM: C[M][N] fp32 = A[M][K] bf16 * Bt[N][K]^T bf16 ----------------
// BM=128, BN=64, BK=64 (two K-planes in LDS); 4 waves (2x2), 16x16x32 MFMA.
// Requires M%128==0, N%64==0, K%64==0 (M=1024, N in {4672,4544}, K=4544).
__global__ __launch_bounds__(256) void gemm_bt_kernel(
    const short* __restrict__ A, const short* __restrict__ Bt, float* __restrict__ C,
    int M, int N, int K) {
  __shared__ short As[2 * 128 * 32];  // plane kk: [128 rows][32 k] (8KB each)
  __shared__ short Bs[2 * 64 * 32];
  const int tid = threadIdx.x;
  const int lane = tid & 63;
  const int wave = tid >> 6;
  const int wr = wave >> 1, wc = wave & 1;
  const int lr = lane & 15, g = lane >> 4;

  // XCD-aware swizzle (bijective when nwg%8==0): group blocks sharing B-panels per XCD.
  const int nwg = gridDim.x;
  int bid = blockIdx.x;
  int wgid = ((nwg & 7) == 0) ? ((bid & 7) * (nwg >> 3) + (bid >> 3)) : bid;
  const int ntm = M >> 7;
  const int tn = wgid / ntm;
  const int tm = wgid % ntm;

  f32x4 acc[4][2] = {};

  // A staging: 1024 chunks of 16B; chunk c: kk=c>>9, row=(c>>2)&127, kof=(c&3)*8+kk*32
  int rowA[4], kofA[4];
#pragma unroll
  for (int iss = 0; iss < 4; ++iss) {
    int c = iss * 256 + wave * 64 + lane;
    rowA[iss] = (c >> 2) & 127;
    kofA[iss] = ((c & 3) * 8) + ((c >> 9) << 5);
  }
  // B staging: 512 chunks; chunk c: kk=c>>8, row=(c>>2)&63, kof=(c&3)*8+kk*32
  int rowB[2], kofB[2];
#pragma unroll
  for (int iss = 0; iss < 2; ++iss) {
    int c = iss * 256 + wave * 64 + lane;
    rowB[iss] = (c >> 2) & 63;
    kofB[iss] = ((c & 3) * 8) + ((c >> 8) << 5);
  }

  char* AsB = (char*)As;
  char* BsB = (char*)Bs;

  for (int k0 = 0; k0 < K; k0 += 64) {
#pragma unroll
    for (int iss = 0; iss < 4; ++iss)
      gload_lds16(A + (size_t)(tm * 128 + rowA[iss]) * K + k0 + kofA[iss],
                  AsB + (iss * 4 + wave) * 1024);
#pragma unroll
    for (int iss = 0; iss < 2; ++iss)
      gload_lds16(Bt + (size_t)(tn * 64 + rowB[iss]) * K + k0 + kofB[iss],
                  BsB + (iss * 4 + wave) * 1024);
    __syncthreads();
    bf16x8 af[2][4], bfr[2][2];
#pragma unroll
    for (int kk = 0; kk < 2; ++kk) {
#pragma unroll
      for (int im = 0; im < 4; ++im)
        af[kk][im] = *(const bf16x8*)(AsB + kk * 8192 + (wr * 64 + im * 16 + lr) * 64 + g * 16);
#pragma unroll
      for (int in = 0; in < 2; ++in)
        bfr[kk][in] = *(const bf16x8*)(BsB + kk * 4096 + (wc * 32 + in * 16 + lr) * 64 + g * 16);
    }
#pragma unroll
    for (int kk = 0; kk < 2; ++kk)
#pragma unroll
      for (int im = 0; im < 4; ++im)
#pragma unroll
        for (int in = 0; in < 2; ++in)
          acc[im][in] = __builtin_amdgcn_mfma_f32_16x16x32_bf16(af[kk][im], bfr[kk][in], acc[im][in], 0, 0, 0);
    __syncthreads();
  }

#pragma unroll
  for (int im = 0; im < 4; ++im) {
#pragma unroll
    for (int in = 0; in < 2; ++in) {
      int row = tm * 128 + wr * 64 + im * 16 + g * 4;
      int col = tn * 64 + wc * 32 + in * 16 + lr;
#pragma unroll
      for (int i = 0; i < 4; ++i)
        C[(size_t)(row + i) * N + col] = acc[im][in][i];
    }
  }
}

// ---------------- split-K attention, stage 1: partials ----------------
// wave-unit u: head = u/160; r = u%160 -> (kv super-block b of 256 keys, 16-row qtile t).
// Swapped QK^T: lane (lr,g) holds P[key=key0+nf*16+4g+i][qrow=q0+lr]; softmax in-register.
__global__ __launch_bounds__(256) void attn_partial_kernel(
    const short* __restrict__ Qb,   // [NH][S][64]
    const short* __restrict__ Kb,   // [S][64]
    const short* __restrict__ Vt,   // [64][S]
    short* __restrict__ Opart,      // [NU][16][64] bf16, normalized
    float* __restrict__ ml) {       // [NU][16][2] f32 (m, l)
  __shared__ short Pl[4][16 * 128];
  const int lane = threadIdx.x & 63, w = threadIdx.x >> 6;
  const int lr = lane & 15, g = lane >> 4;
  const int u = blockIdx.x * 4 + w;
  const int head = u / UPH;
  const int r = u - head * UPH;
  int b, t;
  if (r < 64)       { b = 0; t = r; }
  else if (r < 112) { b = 1; t = 16 + (r - 64); }
  else if (r < 144) { b = 2; t = 32 + (r - 112); }
  else              { b = 3; t = 48 + (r - 144); }
  const int q0 = t * 16;
  const int qrow = q0 + lr;
  const int key_base = b * 256;
  const int ntr = (key_base + 128 <= q0 + 15) ? 2 : 1;
  short* P = Pl[w];
  const int swz = (((lr >> 2) & 3) << 5) | ((lr & 3) << 4);

  const short* qrp = Qb + ((size_t)head * S + qrow) * 64 + g * 8;
  bf16x8 aQ0 = *(const bf16x8*)(qrp);
  bf16x8 aQ1 = *(const bf16x8*)(qrp + 32);

  f32x4 accO[4] = {};
  float m = -3e30f, l = 0.f;

  for (int tr = 0; tr < ntr; ++tr) {
    const int key0 = key_base + tr * 128;
    f32x4 p[8];
#pragma unroll
    for (int nf = 0; nf < 8; ++nf) {
      const short* krow = Kb + (size_t)(key0 + nf * 16 + lr) * 64 + g * 8;
      bf16x8 k0v = *(const bf16x8*)(krow);
      bf16x8 k1v = *(const bf16x8*)(krow + 32);
      f32x4 z = {};
      z = __builtin_amdgcn_mfma_f32_16x16x32_bf16(k0v, aQ0, z, 0, 0, 0);
      p[nf] = __builtin_amdgcn_mfma_f32_16x16x32_bf16(k1v, aQ1, z, 0, 0, 0);
    }
    // scale (log2-domain) + causal mask + max (in-register: lane owns one q-row)
    float pmx[4] = {-3e30f, -3e30f, -3e30f, -3e30f};
#pragma unroll
    for (int nf = 0; nf < 8; ++nf)
#pragma unroll
      for (int i = 0; i < 4; ++i) {
        int key = key0 + nf * 16 + 4 * g + i;
        float sv = p[nf][i] * K2 + (key <= qrow ? 0.0f : -1e30f);
        p[nf][i] = sv;
        pmx[i] = fmaxf(pmx[i], sv);
      }
    float pm = fmaxf(fmaxf(pmx[0], pmx[1]), fmaxf(pmx[2], pmx[3]));
    pm = fmaxf(pm, __shfl_xor(pm, 16));
    pm = fmaxf(pm, __shfl_xor(pm, 32));
    float mn = fmaxf(m, pm);
    float scl = __builtin_exp2f(m - mn);
    m = mn;
    float rsx[4] = {0.f, 0.f, 0.f, 0.f};
#pragma unroll
    for (int nf = 0; nf < 8; ++nf)
#pragma unroll
      for (int i = 0; i < 4; ++i) {
        float pe = __builtin_exp2f(p[nf][i] - m);
        p[nf][i] = pe;
        rsx[i] += pe;
      }
    float rs = (rsx[0] + rsx[1]) + (rsx[2] + rsx[3]);
    rs += __shfl_xor(rs, 16);
    rs += __shfl_xor(rs, 32);
    l = l * scl + rs;
    // pack P -> LDS row-major [qrow=lr][key], swizzled; lane's 4 keys are contiguous
#pragma unroll
    for (int nf = 0; nf < 8; ++nf) {
      uint2 wv;
      wv.x = cvt_pk_bf16(p[nf][0], p[nf][1]);
      wv.y = cvt_pk_bf16(p[nf][2], p[nf][3]);
      *(uint2*)((char*)P + lr * 256 + ((nf * 32 + g * 8) ^ swz)) = wv;
    }
    // rescale accO (rows 4g+i live at lane lr'=4g+i)
#pragma unroll
    for (int i = 0; i < 4; ++i) {
      float si = __shfl(scl, 4 * g + i);
#pragma unroll
      for (int df = 0; df < 4; ++df)
        accO[df][i] *= si;
    }
    // PV: A = P rows (qrow=lr, k=key), B = V cols (d=lr, k=key)
#pragma unroll
    for (int kk = 0; kk < 4; ++kk) {
      bf16x8 aP = *(const bf16x8*)((char*)P + lr * 256 + ((kk * 64 + g * 16) ^ swz));
#pragma unroll
      for (int df = 0; df < 4; ++df) {
        bf16x8 bV = *(const bf16x8*)(Vt + (size_t)(df * 16 + lr) * S + key0 + kk * 32 + g * 8);
        accO[df] = __builtin_amdgcn_mfma_f32_16x16x32_bf16(aP, bV, accO[df], 0, 0, 0);
      }
    }
  }
  // write normalized partial + (m,l)
#pragma unroll
  for (int i = 0; i < 4; ++i) {
    float li = __shfl(l, 4 * g + i);
    float rli = 1.0f / li;
#pragma unroll
    for (int df = 0; df < 4; ++df)
      Opart[((size_t)u * 16 + 4 * g + i) * 64 + df * 16 + lr] = f2bf(accO[df][i] * rli);
  }
  if (g == 0) {
    float2 v; v.x = m; v.y = l;
    ((float2*)ml)[(size_t)u * 16 + lr] = v;
  }
}

// ---------------- split-K attention, stage 2: reduce ----------------
__global__ __launch_bounds__(64) void attn_reduce_kernel(
    const short* __restrict__ Opart, const float* __restrict__ ml,
    short* __restrict__ merged) {  // [S][H] bf16
  const int t = blockIdx.x, head = blockIdx.y, d = threadIdx.x;
  const int nb = t / 16 + 1;
  for (int r = 0; r < 16; ++r) {
    int qrow = t * 16 + r;
    float mv[4], lv[4];
    float M = -3e30f;
#pragma unroll 4
    for (int b = 0; b < nb; ++b) {
      int u = head * UPH + d_off4[b] + (t - 16 * b);
      float2 v = ((const float2*)ml)[(size_t)u * 16 + r];
      mv[b] = v.x; lv[b] = v.y;
      M = fmaxf(M, v.x);
    }
    float den = 0.f, o = 0.f;
#pragma unroll 4
    for (int b = 0; b < nb; ++b) {
      int u = head * UPH + d_off4[b] + (t - 16 * b);
      float wgt = __builtin_exp2f(mv[b] - M) * lv[b];
      den += wgt;
      o += wgt * bf2f(Opart[((size_t)u * 16 + r) * 64 + d]);
    }
    merged[(size_t)qrow * H + head * 64 + d] = f2bf(o / den);
  }
}

extern "C" void kernel_launch(void* const* d_in, const int* in_sizes, int n_in,
                              void* d_out, int out_size, void* d_ws, size_t ws_size,
                              hipStream_t stream) {
  const float* x    = (const float*)d_in[0];
  const float* wqkv = (const float*)d_in[1];
  const float* wd   = (const float*)d_in[2];
  // d_in[3] attention_mask: pure causal, applied analytically
  float* out = (float*)d_out;

  char* ws = (char*)d_ws;
  size_t off = 0;
  short* Wqkvt  = (short*)(ws + off); off += (size_t)F * H * 2;       // [F][H]
  short* Wdt    = (short*)(ws + off); off += (size_t)H * H * 2;       // [H][H]
  short* Qb     = (short*)(ws + off); off += (size_t)NH * S * HD * 2; // [NH][S][64]
  short* Kb     = (short*)(ws + off); off += (size_t)S * HD * 2;
  short* Vtb    = (short*)(ws + off); off += (size_t)HD * S * 2;
  short* merged = (short*)(ws + off); off += (size_t)S * H * 2;       // [S][H]
  float* ct     = (float*)(ws + off); off += (size_t)S * 32 * 4;
  float* st     = (float*)(ws + off); off += (size_t)S * 32 * 4;
  char* regionX = ws + off;                                           // union region
  short* xb     = (short*)regionX;                      // [S][H] bf16 (phase 1)
  float* qkv    = (float*)(regionX + (size_t)S * H * 2);// [S][F] f32 (phase 1)
  short* Opart  = (short*)regionX;                      // [NU][16][64] bf16 (phase 2)
  float* ml     = (float*)(regionX + (size_t)NU * 16 * 64 * 2);  // [NU][16][2] f32
  (void)ws_size; (void)in_sizes; (void)n_in; (void)out_size;

  hipLaunchKernelGGL(cast_x_kernel, dim3((S * H / 4 + 255) / 256), dim3(256), 0, stream,
                     x, xb, S * H / 4);
  hipLaunchKernelGGL(transpose_cast_kernel, dim3(F / 64, H / 64), dim3(256), 0, stream,
                     wqkv, Wqkvt, H, F);
  hipLaunchKernelGGL(transpose_cast_kernel, dim3(H / 64, H / 64), dim3(256), 0, stream,
                     wd, Wdt, H, H);
  hipLaunchKernelGGL(rope_tables_kernel, dim3(S), dim3(32), 0, stream, ct, st);
  hipLaunchKernelGGL(gemm_bt_kernel, dim3((F / 64) * (S / 128)), dim3(256), 0, stream,
                     xb, Wqkvt, qkv, S, F, H);
  hipLaunchKernelGGL(rope_pack_kernel, dim3(S), dim3(256), 0, stream,
                     qkv, ct, st, Qb, Kb, Vtb);
  hipLaunchKernelGGL(attn_partial_kernel, dim3(NU / 4), dim3(256), 0, stream,
                     Qb, Kb, Vtb, Opart, ml);
  hipLaunchKernelGGL(attn_reduce_kernel, dim3(S / 16, NH), dim3(64), 0, stream,
                     Opart, ml, merged);
  hipLaunchKernelGGL(gemm_bt_kernel, dim3((H / 64) * (S / 128)), dim3(256), 0, stream,
                     merged, Wdt, out, S, H, H);
}

// Round 4
// 320.742 us; speedup vs baseline: 1.4086x; 1.0654x over previous
//
#include <hip/hip_runtime.h>
#include <hip/hip_bf16.h>

#define DI __device__ __forceinline__

typedef __attribute__((ext_vector_type(8))) short bf16x8;
typedef __attribute__((ext_vector_type(4))) float f32x4;
typedef __attribute__((ext_vector_type(4))) short s16x4;

constexpr int S  = 1024;
constexpr int NH = 71;
constexpr int HD = 64;
constexpr int H  = NH * HD;        // 4544
constexpr int F  = (NH + 2) * HD;  // 4672
constexpr float K2 = 0.125f * 1.44269504f;  // SCALE * log2(e)

// split-K attention: unit = (head, 16 q-rows, 256 keys). per head: 160 units.
constexpr int UPH = 160;
constexpr int NU  = NH * UPH;            // 11360
__device__ __constant__ int d_off4[4] = {0, 64, 112, 144};

DI short f2bf(float f) {
  union { float f; unsigned u; } v; v.f = f;
  unsigned r = v.u + 0x7fffu + ((v.u >> 16) & 1u);
  return (short)(r >> 16);
}
DI float bf2f(short b) {
  union { unsigned u; float f; } v; v.u = ((unsigned)(unsigned short)b) << 16;
  return v.f;
}
DI unsigned cvt_pk_bf16(float lo, float hi) {
  unsigned r;
  asm("v_cvt_pk_bf16_f32 %0, %1, %2" : "=v"(r) : "v"(lo), "v"(hi));
  return r;
}
// reduce over lanes {lr, lr+16, lr+32, lr+48}: xor16 via ds_swizzle, xor32 via shfl
DI float redmax_g(float x) {
  float y = fmaxf(x, __int_as_float(__builtin_amdgcn_ds_swizzle(__float_as_int(x), 0x401F)));
  return fmaxf(y, __shfl_xor(y, 32));
}
DI float redsum_g(float x) {
  float y = x + __int_as_float(__builtin_amdgcn_ds_swizzle(__float_as_int(x), 0x401F));
  return y + __shfl_xor(y, 32);
}

DI void gload_lds16(const void* g, void* l) {
  __builtin_amdgcn_global_load_lds(
      (const __attribute__((address_space(1))) unsigned int*)g,
      (__attribute__((address_space(3))) unsigned int*)l, 16, 0, 0);
}

// ---------------- cast x fp32 -> bf16 ----------------
__global__ void cast_x_kernel(const float* __restrict__ x, short* __restrict__ xb, int n4) {
  int i = blockIdx.x * blockDim.x + threadIdx.x;
  if (i >= n4) return;
  f32x4 v = ((const f32x4*)x)[i];
  s16x4 o = { f2bf(v.x), f2bf(v.y), f2bf(v.z), f2bf(v.w) };
  ((s16x4*)xb)[i] = o;
}

// ---------------- transpose + cast: W[K][N] fp32 -> Wt[N][K] bf16 ----------------
__global__ __launch_bounds__(256) void transpose_cast_kernel(
    const float* __restrict__ W, short* __restrict__ Wt, int K, int N) {
  __shared__ float tile[64][65];
  int n0 = blockIdx.x * 64, k0 = blockIdx.y * 64;
  int c = threadIdx.x & 63, rg = threadIdx.x >> 6;
#pragma unroll
  for (int i = 0; i < 16; ++i) {
    int r = rg * 16 + i;
    tile[r][c] = W[(size_t)(k0 + r) * N + n0 + c];
  }
  __syncthreads();
#pragma unroll
  for (int i = 0; i < 16; ++i) {
    int r = rg * 16 + i;
    Wt[(size_t)(n0 + r) * K + k0 + c] = f2bf(tile[c][r]);
  }
}

// ---------------- RoPE tables ----------------
__global__ void rope_tables_kernel(float* __restrict__ ct, float* __restrict__ st) {
  int s = blockIdx.x, i = threadIdx.x;  // 32 threads
  float invf = powf(10000.0f, -(float)i / 32.0f);
  float a = (float)s * invf;
  ct[s * 32 + i] = cosf(a);
  st[s * 32 + i] = sinf(a);
}

// ---------------- RoPE + pack ----------------
__global__ __launch_bounds__(256) void rope_pack_kernel(
    const float* __restrict__ qkv, const float* __restrict__ ct, const float* __restrict__ st,
    short* __restrict__ Qb, short* __restrict__ Kb, short* __restrict__ Vt) {
  int s = blockIdx.x;
  const float* row = qkv + (size_t)s * F;
  for (int c = threadIdx.x; c < F; c += 256) {
    int hh = c >> 6, d = c & 63;
    float v = row[c];
    if (hh <= NH) {
      int i = d & 31;
      float cs = ct[s * 32 + i], sn = st[s * 32 + i];
      float rot = (d < 32) ? -row[c + 32] : row[c - 32];
      short ob = f2bf(v * cs + rot * sn);
      if (hh < NH) Qb[((size_t)hh * S + s) * 64 + d] = ob;
      else         Kb[(size_t)s * 64 + d] = ob;
    } else {
      Vt[(size_t)d * S + s] = f2bf(v);
    }
  }
}

// ---------------- GEMM: C[M][N] = A[M][K] * Bt[N][K]^T, 2-phase pipeline ----------------
// BM=128, BN=64, BK=64; double-buffered LDS (48KB); XOR-swizzled chunks (2-way floor).
__global__ __launch_bounds__(256, 3) void gemm_bt_kernel(
    const short* __restrict__ A, const short* __restrict__ Bt, float* __restrict__ C,
    int M, int N, int K) {
  __shared__ short As[2 * 128 * 64];  // 2 x 16KB, per buf: 2 planes x [128 rows][32k]
  __shared__ short Bs[2 * 64 * 64];   // 2 x 8KB
  const int tid = threadIdx.x;
  const int lane = tid & 63;
  const int wave = tid >> 6;
  const int wr = wave >> 1, wc = wave & 1;
  const int lr = lane & 15, g = lane >> 4;

  const int nwg = gridDim.x;
  int bid = blockIdx.x;
  int wgid = ((nwg & 7) == 0) ? ((bid & 7) * (nwg >> 3) + (bid >> 3)) : bid;
  const int ntm = M >> 7;
  const int tn = wgid / ntm;
  const int tm = wgid % ntm;

  f32x4 acc[4][2] = {};

  // staging src: dest chunk d -> plane=d>>9(A)/d>>8(B), row, physical slot c'=d&3,
  // logical chunk c = c' ^ ((row>>1)&3)  (XOR swizzle, rule-21: linear dest + permuted src)
  int srowA[4], skofA[4];
#pragma unroll
  for (int iss = 0; iss < 4; ++iss) {
    int d = iss * 256 + wave * 64 + lane;
    int row = (d >> 2) & 127;
    int c = (d & 3) ^ ((row >> 1) & 3);
    srowA[iss] = row;
    skofA[iss] = ((d >> 9) << 5) + c * 8;
  }
  int srowB[2], skofB[2];
#pragma unroll
  for (int iss = 0; iss < 2; ++iss) {
    int d = iss * 256 + wave * 64 + lane;
    int row = (d >> 2) & 63;
    int c = (d & 3) ^ ((row >> 1) & 3);
    srowB[iss] = row;
    skofB[iss] = ((d >> 8) << 5) + c * 8;
  }
  // read byte-offsets (within buffer), swizzled to match
  int offA[2][4], offB[2][2];
#pragma unroll
  for (int im = 0; im < 4; ++im) {
    int row_a = wr * 64 + im * 16 + lr;
    int sl = (g ^ ((row_a >> 1) & 3)) << 4;
#pragma unroll
    for (int kk = 0; kk < 2; ++kk) offA[kk][im] = kk * 8192 + row_a * 64 + sl;
  }
#pragma unroll
  for (int in = 0; in < 2; ++in) {
    int row_b = wc * 32 + in * 16 + lr;
    int sl = (g ^ ((row_b >> 1) & 3)) << 4;
#pragma unroll
    for (int kk = 0; kk < 2; ++kk) offB[kk][in] = kk * 4096 + row_b * 64 + sl;
  }

  char* AsB = (char*)As;
  char* BsB = (char*)Bs;
  const size_t Abase = (size_t)tm * 128 * K;
  const size_t Bbase = (size_t)tn * 64 * K;

#define STAGE(buf, k0)                                                                  \
  {                                                                                     \
    _Pragma("unroll")                                                                   \
    for (int iss = 0; iss < 4; ++iss)                                                   \
      gload_lds16(A + Abase + (size_t)srowA[iss] * K + (k0) + skofA[iss],               \
                  AsB + (buf) * 16384 + (iss * 4 + wave) * 1024);                       \
    _Pragma("unroll")                                                                   \
    for (int iss = 0; iss < 2; ++iss)                                                   \
      gload_lds16(Bt + Bbase + (size_t)srowB[iss] * K + (k0) + skofB[iss],              \
                  BsB + (buf) * 8192 + (iss * 4 + wave) * 1024);                        \
  }

  STAGE(0, 0);
  __syncthreads();
  const int KS = K >> 6;
  for (int t = 0; t < KS; ++t) {
    const int cur = t & 1;
    if (t + 1 < KS) STAGE(cur ^ 1, (t + 1) << 6);
    const char* Ac = AsB + cur * 16384;
    const char* Bc = BsB + cur * 8192;
    bf16x8 af[2][4], bfr[2][2];
#pragma unroll
    for (int kk = 0; kk < 2; ++kk) {
#pragma unroll
      for (int im = 0; im < 4; ++im) af[kk][im] = *(const bf16x8*)(Ac + offA[kk][im]);
#pragma unroll
      for (int in = 0; in < 2; ++in) bfr[kk][in] = *(const bf16x8*)(Bc + offB[kk][in]);
    }
#pragma unroll
    for (int kk = 0; kk < 2; ++kk)
#pragma unroll
      for (int im = 0; im < 4; ++im)
#pragma unroll
        for (int in = 0; in < 2; ++in)
          acc[im][in] = __builtin_amdgcn_mfma_f32_16x16x32_bf16(af[kk][im], bfr[kk][in], acc[im][in], 0, 0, 0);
    __syncthreads();
  }
#undef STAGE

#pragma unroll
  for (int im = 0; im < 4; ++im) {
#pragma unroll
    for (int in = 0; in < 2; ++in) {
      int row = tm * 128 + wr * 64 + im * 16 + g * 4;
      int col = tn * 64 + wc * 32 + in * 16 + lr;
#pragma unroll
      for (int i = 0; i < 4; ++i)
        C[(size_t)(row + i) * N + col] = acc[im][in][i];
    }
  }
}

// ---------------- split-K attention, stage 1 (1 wave / WG, fully swapped) ----------------
// Swapped QK^T: lane(lr,g) holds P[key0+16nf+4g+i][qrow=q0+lr].
// Swapped PV:   lane(lr,g) holds O[d=16df+4g+i][qrow=q0+lr] -> m,l,scl all per-lane.
__global__ __launch_bounds__(64, 4) void attn_partial_kernel(
    const short* __restrict__ Qb,   // [NH][S][64]
    const short* __restrict__ Kb,   // [S][64]
    const short* __restrict__ Vt,   // [64][S]
    short* __restrict__ Opart,      // [NU][64 d][16 q] bf16, normalized
    float* __restrict__ ml) {       // [NU][16][2] f32 (m, l)
  __shared__ short P[16 * 136];     // [qrow][272B padded row] -> ~2-way banks
  const int lane = threadIdx.x;
  const int lr = lane & 15, g = lane >> 4;
  const int u = blockIdx.x;
  const int head = u / UPH;
  const int r = u - head * UPH;
  int b, t;
  if (r < 64)       { b = 0; t = r; }
  else if (r < 112) { b = 1; t = 16 + (r - 64); }
  else if (r < 144) { b = 2; t = 32 + (r - 112); }
  else              { b = 3; t = 48 + (r - 144); }
  const int q0 = t * 16;
  const int qrow = q0 + lr;
  const int key_base = b * 256;
  const int ntr = (key_base + 128 <= q0 + 15) ? 2 : 1;

  const short* qrp = Qb + ((size_t)head * S + qrow) * 64 + g * 8;
  bf16x8 aQ0 = *(const bf16x8*)(qrp);
  bf16x8 aQ1 = *(const bf16x8*)(qrp + 32);

  f32x4 accO[4] = {};
  float m = -3e30f, l = 0.f;

  for (int tr = 0; tr < ntr; ++tr) {
    const int key0 = key_base + tr * 128;
    f32x4 p[8];
#pragma unroll
    for (int nf = 0; nf < 8; ++nf) {
      const short* krow = Kb + (size_t)(key0 + nf * 16 + lr) * 64 + g * 8;
      bf16x8 k0v = *(const bf16x8*)(krow);
      bf16x8 k1v = *(const bf16x8*)(krow + 32);
      f32x4 z = {};
      z = __builtin_amdgcn_mfma_f32_16x16x32_bf16(k0v, aQ0, z, 0, 0, 0);
      p[nf] = __builtin_amdgcn_mfma_f32_16x16x32_bf16(k1v, aQ1, z, 0, 0, 0);
    }
    // scale (log2-domain) + causal mask + in-register max
    float pmx = -3e30f;
#pragma unroll
    for (int nf = 0; nf < 8; ++nf)
#pragma unroll
      for (int i = 0; i < 4; ++i) {
        int key = key0 + nf * 16 + 4 * g + i;
        float sv = p[nf][i] * K2 + (key <= qrow ? 0.0f : -1e30f);
        p[nf][i] = sv;
        pmx = fmaxf(pmx, sv);
      }
    float pm = redmax_g(pmx);
    float mn = fmaxf(m, pm);
    float scl = __builtin_exp2f(m - mn);
    m = mn;
    // exp + pack P to LDS [qrow=lr][key] (write early, overlap with sum-reduce)
    float rsx = 0.f;
#pragma unroll
    for (int nf = 0; nf < 8; ++nf) {
      f32x4 pe;
#pragma unroll
      for (int i = 0; i < 4; ++i) {
        pe[i] = __builtin_exp2f(p[nf][i] - m);
        rsx += pe[i];
      }
      uint2 wv;
      wv.x = cvt_pk_bf16(pe[0], pe[1]);
      wv.y = cvt_pk_bf16(pe[2], pe[3]);
      *(uint2*)((char*)P + lr * 272 + nf * 32 + g * 8) = wv;
    }
    float rs = redsum_g(rsx);
    l = l * scl + rs;
    // rescale accO: per-lane scalar (qrow = lr for every element)
#pragma unroll
    for (int df = 0; df < 4; ++df)
#pragma unroll
      for (int i = 0; i < 4; ++i)
        accO[df][i] *= scl;
    // PV: O^T = V^T * P  (A = V rows d, B = P cols qrow)
#pragma unroll
    for (int kk = 0; kk < 4; ++kk) {
      bf16x8 aP = *(const bf16x8*)((char*)P + lr * 272 + kk * 64 + g * 16);
#pragma unroll
      for (int df = 0; df < 4; ++df) {
        bf16x8 bV = *(const bf16x8*)(Vt + (size_t)(df * 16 + lr) * S + key0 + kk * 32 + g * 8);
        accO[df] = __builtin_amdgcn_mfma_f32_16x16x32_bf16(bV, aP, accO[df], 0, 0, 0);
      }
    }
  }
  // write normalized partial (per-lane l!) + (m,l)
  float rl = 1.0f / l;
#pragma unroll
  for (int df = 0; df < 4; ++df)
#pragma unroll
    for (int i = 0; i < 4; ++i)
      Opart[(size_t)u * 1024 + (df * 16 + 4 * g + i) * 16 + lr] = f2bf(accO[df][i] * rl);
  if (g == 0) {
    float2 v; v.x = m; v.y = l;
    ((float2*)ml)[(size_t)u * 16 + lr] = v;
  }
}

// ---------------- split-K attention, stage 2: reduce ----------------
__global__ __launch_bounds__(64) void attn_reduce_kernel(
    const short* __restrict__ Opart,  // [NU][64][16]
    const float* __restrict__ ml,
    short* __restrict__ merged) {     // [S][H] bf16
  const int t = blockIdx.x, head = blockIdx.y, d = threadIdx.x;
  const int nb = t / 16 + 1;
  for (int r = 0; r < 16; ++r) {
    int qrow = t * 16 + r;
    float mv[4], lv[4];
    float M = -3e30f;
#pragma unroll 4
    for (int b = 0; b < nb; ++b) {
      int u = head * UPH + d_off4[b] + (t - 16 * b);
      float2 v = ((const float2*)ml)[(size_t)u * 16 + r];
      mv[b] = v.x; lv[b] = v.y;
      M = fmaxf(M, v.x);
    }
    float den = 0.f, o = 0.f;
#pragma unroll 4
    for (int b = 0; b < nb; ++b) {
      int u = head * UPH + d_off4[b] + (t - 16 * b);
      float wgt = __builtin_exp2f(mv[b] - M) * lv[b];
      den += wgt;
      o += wgt * bf2f(Opart[(size_t)u * 1024 + d * 16 + r]);
    }
    merged[(size_t)qrow * H + head * 64 + d] = f2bf(o / den);
  }
}

extern "C" void kernel_launch(void* const* d_in, const int* in_sizes, int n_in,
                              void* d_out, int out_size, void* d_ws, size_t ws_size,
                              hipStream_t stream) {
  const float* x    = (const float*)d_in[0];
  const float* wqkv = (const float*)d_in[1];
  const float* wd   = (const float*)d_in[2];
  // d_in[3] attention_mask: pure causal, applied analytically
  float* out = (float*)d_out;

  char* ws = (char*)d_ws;
  size_t off = 0;
  short* Wqkvt  = (short*)(ws + off); off += (size_t)F * H * 2;       // [F][H]
  short* Wdt    = (short*)(ws + off); off += (size_t)H * H * 2;       // [H][H]
  short* Qb     = (short*)(ws + off); off += (size_t)NH * S * HD * 2; // [NH][S][64]
  short* Kb     = (short*)(ws + off); off += (size_t)S * HD * 2;
  short* Vtb    = (short*)(ws + off); off += (size_t)HD * S * 2;
  short* merged = (short*)(ws + off); off += (size_t)S * H * 2;       // [S][H]
  float* ct     = (float*)(ws + off); off += (size_t)S * 32 * 4;
  float* st     = (float*)(ws + off); off += (size_t)S * 32 * 4;
  char* regionX = ws + off;                                           // union region
  short* xb     = (short*)regionX;                      // [S][H] bf16 (phase 1)
  float* qkv    = (float*)(regionX + (size_t)S * H * 2);// [S][F] f32 (phase 1)
  short* Opart  = (short*)regionX;                      // [NU][64][16] bf16 (phase 2)
  float* ml     = (float*)(regionX + (size_t)NU * 16 * 64 * 2);  // [NU][16][2] f32
  (void)ws_size; (void)in_sizes; (void)n_in; (void)out_size;

  hipLaunchKernelGGL(cast_x_kernel, dim3((S * H / 4 + 255) / 256), dim3(256), 0, stream,
                     x, xb, S * H / 4);
  hipLaunchKernelGGL(transpose_cast_kernel, dim3(F / 64, H / 64), dim3(256), 0, stream,
                     wqkv, Wqkvt, H, F);
  hipLaunchKernelGGL(transpose_cast_kernel, dim3(H / 64, H / 64), dim3(256), 0, stream,
                     wd, Wdt, H, H);
  hipLaunchKernelGGL(rope_tables_kernel, dim3(S), dim3(32), 0, stream, ct, st);
  hipLaunchKernelGGL(gemm_bt_kernel, dim3((F / 64) * (S / 128)), dim3(256), 0, stream,
                     xb, Wqkvt, qkv, S, F, H);
  hipLaunchKernelGGL(rope_pack_kernel, dim3(S), dim3(256), 0, stream,
                     qkv, ct, st, Qb, Kb, Vtb);
  hipLaunchKernelGGL(attn_partial_kernel, dim3(NU), dim3(64), 0, stream,
                     Qb, Kb, Vtb, Opart, ml);
  hipLaunchKernelGGL(attn_reduce_kernel, dim3(S / 16, NH), dim3(64), 0, stream,
                     Opart, ml, merged);
  hipLaunchKernelGGL(gemm_bt_kernel, dim3((H / 64) * (S / 128)), dim3(256), 0, stream,
                     merged, Wdt, out, S, H, H);
}

// Round 5
// 239.594 us; speedup vs baseline: 1.8856x; 1.3387x over previous
//
#include <hip/hip_runtime.h>
#include <hip/hip_bf16.h>

#define DI __device__ __forceinline__

typedef __attribute__((ext_vector_type(8))) short bf16x8;
typedef __attribute__((ext_vector_type(4))) float f32x4;
typedef __attribute__((ext_vector_type(4))) short s16x4;

constexpr int S  = 1024;
constexpr int NH = 71;
constexpr int HD = 64;
constexpr int H  = NH * HD;        // 4544
constexpr int F  = (NH + 2) * HD;  // 4672
constexpr float K2 = 0.125f * 1.44269504f;  // SCALE * log2(e)

DI short f2bf(float f) {
  union { float f; unsigned u; } v; v.f = f;
  unsigned r = v.u + 0x7fffu + ((v.u >> 16) & 1u);
  return (short)(r >> 16);
}
DI unsigned cvt_pk_bf16(float lo, float hi) {
  unsigned r;
  asm("v_cvt_pk_bf16_f32 %0, %1, %2" : "=v"(r) : "v"(lo), "v"(hi));
  return r;
}
// reduce over lanes {lr, lr+16, lr+32, lr+48}: xor16 via ds_swizzle, xor32 via shfl
DI float redmax_g(float x) {
  float y = fmaxf(x, __int_as_float(__builtin_amdgcn_ds_swizzle(__float_as_int(x), 0x401F)));
  return fmaxf(y, __shfl_xor(y, 32));
}
DI float redsum_g(float x) {
  float y = x + __int_as_float(__builtin_amdgcn_ds_swizzle(__float_as_int(x), 0x401F));
  return y + __shfl_xor(y, 32);
}

DI void gload_lds16(const void* g, void* l) {
  __builtin_amdgcn_global_load_lds(
      (const __attribute__((address_space(1))) unsigned int*)g,
      (__attribute__((address_space(3))) unsigned int*)l, 16, 0, 0);
}

// swizzled LDS tile read: [64 rows][8 slots of 16B], slot XOR row&7
DI bf16x8 ldswz(const char* base, int row, int slot) {
  return *(const bf16x8*)(base + row * 128 + ((slot ^ (row & 7)) << 4));
}

// ---------------- cast x fp32 -> bf16 ----------------
__global__ void cast_x_kernel(const float* __restrict__ x, short* __restrict__ xb, int n4) {
  int i = blockIdx.x * blockDim.x + threadIdx.x;
  if (i >= n4) return;
  f32x4 v = ((const f32x4*)x)[i];
  s16x4 o = { f2bf(v.x), f2bf(v.y), f2bf(v.z), f2bf(v.w) };
  ((s16x4*)xb)[i] = o;
}

// ---------------- transpose + cast: W[K][N] fp32 -> Wt[N][K] bf16 ----------------
__global__ __launch_bounds__(256) void transpose_cast_kernel(
    const float* __restrict__ W, short* __restrict__ Wt, int K, int N) {
  __shared__ float tile[64][65];
  int n0 = blockIdx.x * 64, k0 = blockIdx.y * 64;
  int c = threadIdx.x & 63, rg = threadIdx.x >> 6;
#pragma unroll
  for (int i = 0; i < 16; ++i) {
    int r = rg * 16 + i;
    tile[r][c] = W[(size_t)(k0 + r) * N + n0 + c];
  }
  __syncthreads();
#pragma unroll
  for (int i = 0; i < 16; ++i) {
    int r = rg * 16 + i;
    Wt[(size_t)(n0 + r) * K + k0 + c] = f2bf(tile[c][r]);
  }
}

// ---------------- RoPE tables ----------------
__global__ void rope_tables_kernel(float* __restrict__ ct, float* __restrict__ st) {
  int s = blockIdx.x, i = threadIdx.x;  // 32 threads
  float invf = powf(10000.0f, -(float)i / 32.0f);
  float a = (float)s * invf;
  ct[s * 32 + i] = cosf(a);
  st[s * 32 + i] = sinf(a);
}

// ---------------- RoPE + pack ----------------
__global__ __launch_bounds__(256) void rope_pack_kernel(
    const float* __restrict__ qkv, const float* __restrict__ ct, const float* __restrict__ st,
    short* __restrict__ Qb, short* __restrict__ Kb, short* __restrict__ Vt) {
  int s = blockIdx.x;
  const float* row = qkv + (size_t)s * F;
  for (int c = threadIdx.x; c < F; c += 256) {
    int hh = c >> 6, d = c & 63;
    float v = row[c];
    if (hh <= NH) {
      int i = d & 31;
      float cs = ct[s * 32 + i], sn = st[s * 32 + i];
      float rot = (d < 32) ? -row[c + 32] : row[c - 32];
      short ob = f2bf(v * cs + rot * sn);
      if (hh < NH) Qb[((size_t)hh * S + s) * 64 + d] = ob;
      else         Kb[(size_t)s * 64 + d] = ob;
    } else {
      Vt[(size_t)d * S + s] = f2bf(v);
    }
  }
}

// ---------------- GEMM: C[M][N] = A[M][K] * Bt[N][K]^T, 2-phase pipeline ----------------
__global__ __launch_bounds__(256, 3) void gemm_bt_kernel(
    const short* __restrict__ A, const short* __restrict__ Bt, float* __restrict__ C,
    int M, int N, int K) {
  __shared__ short As[2 * 128 * 64];
  __shared__ short Bs[2 * 64 * 64];
  const int tid = threadIdx.x;
  const int lane = tid & 63;
  const int wave = tid >> 6;
  const int wr = wave >> 1, wc = wave & 1;
  const int lr = lane & 15, g = lane >> 4;

  const int nwg = gridDim.x;
  int bid = blockIdx.x;
  int wgid = ((nwg & 7) == 0) ? ((bid & 7) * (nwg >> 3) + (bid >> 3)) : bid;
  const int ntm = M >> 7;
  const int tn = wgid / ntm;
  const int tm = wgid % ntm;

  f32x4 acc[4][2] = {};

  int srowA[4], skofA[4];
#pragma unroll
  for (int iss = 0; iss < 4; ++iss) {
    int d = iss * 256 + wave * 64 + lane;
    int row = (d >> 2) & 127;
    int c = (d & 3) ^ ((row >> 1) & 3);
    srowA[iss] = row;
    skofA[iss] = ((d >> 9) << 5) + c * 8;
  }
  int srowB[2], skofB[2];
#pragma unroll
  for (int iss = 0; iss < 2; ++iss) {
    int d = iss * 256 + wave * 64 + lane;
    int row = (d >> 2) & 63;
    int c = (d & 3) ^ ((row >> 1) & 3);
    srowB[iss] = row;
    skofB[iss] = ((d >> 8) << 5) + c * 8;
  }
  int offA[2][4], offB[2][2];
#pragma unroll
  for (int im = 0; im < 4; ++im) {
    int row_a = wr * 64 + im * 16 + lr;
    int sl = (g ^ ((row_a >> 1) & 3)) << 4;
#pragma unroll
    for (int kk = 0; kk < 2; ++kk) offA[kk][im] = kk * 8192 + row_a * 64 + sl;
  }
#pragma unroll
  for (int in = 0; in < 2; ++in) {
    int row_b = wc * 32 + in * 16 + lr;
    int sl = (g ^ ((row_b >> 1) & 3)) << 4;
#pragma unroll
    for (int kk = 0; kk < 2; ++kk) offB[kk][in] = kk * 4096 + row_b * 64 + sl;
  }

  char* AsB = (char*)As;
  char* BsB = (char*)Bs;
  const size_t Abase = (size_t)tm * 128 * K;
  const size_t Bbase = (size_t)tn * 64 * K;

#define STAGE(buf, k0)                                                                  \
  {                                                                                     \
    _Pragma("unroll")                                                                   \
    for (int iss = 0; iss < 4; ++iss)                                                   \
      gload_lds16(A + Abase + (size_t)srowA[iss] * K + (k0) + skofA[iss],               \
                  AsB + (buf) * 16384 + (iss * 4 + wave) * 1024);                       \
    _Pragma("unroll")                                                                   \
    for (int iss = 0; iss < 2; ++iss)                                                   \
      gload_lds16(Bt + Bbase + (size_t)srowB[iss] * K + (k0) + skofB[iss],              \
                  BsB + (buf) * 8192 + (iss * 4 + wave) * 1024);                        \
  }

  STAGE(0, 0);
  __syncthreads();
  const int KS = K >> 6;
  for (int t = 0; t < KS; ++t) {
    const int cur = t & 1;
    if (t + 1 < KS) STAGE(cur ^ 1, (t + 1) << 6);
    const char* Ac = AsB + cur * 16384;
    const char* Bc = BsB + cur * 8192;
    bf16x8 af[2][4], bfr[2][2];
#pragma unroll
    for (int kk = 0; kk < 2; ++kk) {
#pragma unroll
      for (int im = 0; im < 4; ++im) af[kk][im] = *(const bf16x8*)(Ac + offA[kk][im]);
#pragma unroll
      for (int in = 0; in < 2; ++in) bfr[kk][in] = *(const bf16x8*)(Bc + offB[kk][in]);
    }
#pragma unroll
    for (int kk = 0; kk < 2; ++kk)
#pragma unroll
      for (int im = 0; im < 4; ++im)
#pragma unroll
        for (int in = 0; in < 2; ++in)
          acc[im][in] = __builtin_amdgcn_mfma_f32_16x16x32_bf16(af[kk][im], bfr[kk][in], acc[im][in], 0, 0, 0);
    __syncthreads();
  }
#undef STAGE

#pragma unroll
  for (int im = 0; im < 4; ++im) {
#pragma unroll
    for (int in = 0; in < 2; ++in) {
      int row = tm * 128 + wr * 64 + im * 16 + g * 4;
      int col = tn * 64 + wc * 32 + in * 16 + lr;
#pragma unroll
      for (int i = 0; i < 4; ++i)
        C[(size_t)(row + i) * N + col] = acc[im][in][i];
    }
  }
}

// ---------------- fused causal MQA attention (paired-strip, LDS-staged KV) ----------------
// One strip-step: QK^T (swapped) -> in-register softmax -> P to LDS -> PV (swapped).
DI void attn_step(const char* Kc, const char* Vc, char* P,
                  int key0, int qrow, bf16x8 aQ0, bf16x8 aQ1,
                  f32x4* accO, float& m, float& l, int lr, int g) {
  f32x4 p[4];
#pragma unroll
  for (int nf = 0; nf < 4; ++nf) {
    int row = nf * 16 + lr;
    bf16x8 k0 = ldswz(Kc, row, g);
    bf16x8 k1 = ldswz(Kc, row, g + 4);
    f32x4 z = {};
    z = __builtin_amdgcn_mfma_f32_16x16x32_bf16(k0, aQ0, z, 0, 0, 0);
    p[nf] = __builtin_amdgcn_mfma_f32_16x16x32_bf16(k1, aQ1, z, 0, 0, 0);
  }
  float pmx = -3e30f;
#pragma unroll
  for (int nf = 0; nf < 4; ++nf)
#pragma unroll
    for (int i = 0; i < 4; ++i) {
      int key = key0 + nf * 16 + 4 * g + i;
      float sv = p[nf][i] * K2 + (key <= qrow ? 0.0f : -1e30f);
      p[nf][i] = sv;
      pmx = fmaxf(pmx, sv);
    }
  float pm = redmax_g(pmx);
  float mn = fmaxf(m, pm);
  float scl = __builtin_exp2f(m - mn);
  m = mn;
  float rsx = 0.f;
#pragma unroll
  for (int nf = 0; nf < 4; ++nf) {
    f32x4 pe;
#pragma unroll
    for (int i = 0; i < 4; ++i) {
      pe[i] = __builtin_exp2f(p[nf][i] - m);
      rsx += pe[i];
    }
    uint2 wv;
    wv.x = cvt_pk_bf16(pe[0], pe[1]);
    wv.y = cvt_pk_bf16(pe[2], pe[3]);
    *(uint2*)(P + lr * 144 + nf * 32 + g * 8) = wv;  // P[q=lr][key], stride 144B
  }
  float rs = redsum_g(rsx);
  l = l * scl + rs;
#pragma unroll
  for (int df = 0; df < 4; ++df)
#pragma unroll
    for (int i = 0; i < 4; ++i)
      accO[df][i] *= scl;
#pragma unroll
  for (int st = 0; st < 2; ++st) {
    bf16x8 bP = *(const bf16x8*)(P + lr * 144 + st * 64 + g * 16);
#pragma unroll
    for (int df = 0; df < 4; ++df) {
      bf16x8 aV = ldswz(Vc, df * 16 + lr, g + 4 * st);
      accO[df] = __builtin_amdgcn_mfma_f32_16x16x32_bf16(aV, bP, accO[df], 0, 0, 0);
    }
  }
}

// Grid (8, 71): WG j handles q-tiles A=j and B=15-j (64 rows each; wave w: rows +16w).
// Uniform 17 strip-trips per wave. KV 64-key blocks double-buffered in LDS.
__global__ __launch_bounds__(256) void attn_kernel(
    const short* __restrict__ Qb,   // [NH][S][64]
    const short* __restrict__ Kb,   // [S][64]
    const short* __restrict__ Vt,   // [64][S]
    short* __restrict__ merged) {   // [S][H] bf16
  __shared__ short Ks[2][4096];     // [64 keys][64 d], swizzled 16B slots
  __shared__ short Vs[2][4096];     // [64 d][64 keys], swizzled
  __shared__ short Ps[4][16 * 72];  // per-wave P, stride 144B
  const int lane = threadIdx.x & 63, w = threadIdx.x >> 6;
  const int lr = lane & 15, g = lane >> 4;
  const int j = blockIdx.x, head = blockIdx.y;
  const int kbmax = 15 - j;
  const int qA = j * 64 + w * 16 + lr;
  const int qB = (15 - j) * 64 + w * 16 + lr;
  char* KsB = (char*)Ks;
  char* VsB = (char*)Vs;
  char* P = (char*)Ps[w];

  int crow[2], cslot[2];
#pragma unroll
  for (int i = 0; i < 2; ++i) {
    int c = (i * 4 + w) * 64 + lane;
    crow[i] = c >> 3;
    cslot[i] = (c & 7) ^ (crow[i] & 7);
  }

  const short* qap = Qb + ((size_t)head * S + qA) * 64 + g * 8;
  bf16x8 aQA0 = *(const bf16x8*)(qap);
  bf16x8 aQA1 = *(const bf16x8*)(qap + 32);
  const short* qbp = Qb + ((size_t)head * S + qB) * 64 + g * 8;
  bf16x8 aQB0 = *(const bf16x8*)(qbp);
  bf16x8 aQB1 = *(const bf16x8*)(qbp + 32);

  f32x4 accA[4] = {}, accB[4] = {};
  float mA = -3e30f, lA = 0.f, mB = -3e30f, lB = 0.f;

#define STAGEKV(buf, key0)                                                       \
  {                                                                              \
    _Pragma("unroll")                                                            \
    for (int i = 0; i < 2; ++i) {                                                \
      gload_lds16(Kb + (size_t)((key0) + crow[i]) * 64 + cslot[i] * 8,           \
                  KsB + (buf) * 8192 + (i * 4 + w) * 1024);                      \
      gload_lds16(Vt + (size_t)crow[i] * S + (key0) + cslot[i] * 8,              \
                  VsB + (buf) * 8192 + (i * 4 + w) * 1024);                      \
    }                                                                            \
  }

  STAGEKV(0, 0);
  for (int kb = 0; kb <= kbmax; ++kb) {
    const int cur = kb & 1;
    __syncthreads();  // drains staging vmcnt; all waves done with buf[cur^1]
    if (kb < kbmax) STAGEKV(cur ^ 1, (kb + 1) * 64);
    const char* Kc = KsB + cur * 8192;
    const char* Vc = VsB + cur * 8192;
    attn_step(Kc, Vc, P, kb * 64, qB, aQB0, aQB1, accB, mB, lB, lr, g);
    if (kb <= j)
      attn_step(Kc, Vc, P, kb * 64, qA, aQA0, aQA1, accA, mA, lA, lr, g);
  }
#undef STAGEKV

  float rlA = 1.0f / lA, rlB = 1.0f / lB;
#pragma unroll
  for (int df = 0; df < 4; ++df)
#pragma unroll
    for (int i = 0; i < 4; ++i) {
      int d = head * 64 + df * 16 + 4 * g + i;
      merged[(size_t)qB * H + d] = f2bf(accB[df][i] * rlB);
      merged[(size_t)qA * H + d] = f2bf(accA[df][i] * rlA);
    }
}

extern "C" void kernel_launch(void* const* d_in, const int* in_sizes, int n_in,
                              void* d_out, int out_size, void* d_ws, size_t ws_size,
                              hipStream_t stream) {
  const float* x    = (const float*)d_in[0];
  const float* wqkv = (const float*)d_in[1];
  const float* wd   = (const float*)d_in[2];
  // d_in[3] attention_mask: pure causal, applied analytically
  float* out = (float*)d_out;

  char* ws = (char*)d_ws;
  size_t off = 0;
  short* Wqkvt  = (short*)(ws + off); off += (size_t)F * H * 2;       // [F][H]
  short* Wdt    = (short*)(ws + off); off += (size_t)H * H * 2;       // [H][H]
  short* Qb     = (short*)(ws + off); off += (size_t)NH * S * HD * 2; // [NH][S][64]
  short* Kb     = (short*)(ws + off); off += (size_t)S * HD * 2;
  short* Vtb    = (short*)(ws + off); off += (size_t)HD * S * 2;
  short* merged = (short*)(ws + off); off += (size_t)S * H * 2;       // [S][H]
  float* ct     = (float*)(ws + off); off += (size_t)S * 32 * 4;
  float* st     = (float*)(ws + off); off += (size_t)S * 32 * 4;
  short* xb     = (short*)(ws + off); off += (size_t)S * H * 2;       // [S][H]
  float* qkv    = (float*)(ws + off); off += (size_t)S * F * 4;       // [S][F]
  (void)ws_size; (void)in_sizes; (void)n_in; (void)out_size;

  hipLaunchKernelGGL(cast_x_kernel, dim3((S * H / 4 + 255) / 256), dim3(256), 0, stream,
                     x, xb, S * H / 4);
  hipLaunchKernelGGL(transpose_cast_kernel, dim3(F / 64, H / 64), dim3(256), 0, stream,
                     wqkv, Wqkvt, H, F);
  hipLaunchKernelGGL(transpose_cast_kernel, dim3(H / 64, H / 64), dim3(256), 0, stream,
                     wd, Wdt, H, H);
  hipLaunchKernelGGL(rope_tables_kernel, dim3(S), dim3(32), 0, stream, ct, st);
  hipLaunchKernelGGL(gemm_bt_kernel, dim3((F / 64) * (S / 128)), dim3(256), 0, stream,
                     xb, Wqkvt, qkv, S, F, H);
  hipLaunchKernelGGL(rope_pack_kernel, dim3(S), dim3(256), 0, stream,
                     qkv, ct, st, Qb, Kb, Vtb);
  hipLaunchKernelGGL(attn_kernel, dim3(8, NH), dim3(256), 0, stream,
                     Qb, Kb, Vtb, merged);
  hipLaunchKernelGGL(gemm_bt_kernel, dim3((H / 64) * (S / 128)), dim3(256), 0, stream,
                     merged, Wdt, out, S, H, H);
}